// Round 14
// baseline (216.750 us; speedup 1.0000x reference)
//
#include <hip/hip_runtime.h>

// VectorQuantizer: z[32,32,64,64] f32 (BCHW), emb[1024,32] f32.
// out = concat( z_q[32,32,64,64] f32 , idx[131072] stored as f32 values ).
//
// R14: in-filter classification + compacted slow paths.
//  filter: MFMA scores (acc init = bq, e pre-scaled by -2), per-lane (m1,i1,
//    m2) with med3; 16-lane ballot per query:
//      pc==1 & no m2-in-margin -> the winner IS the argmin: write idx here.
//      2<=pc<=4 & no m2-in-margin -> cand[4] + append query to list A.
//      else -> append to list B (exact full scan).
//  vq_rescore: list A compacted, 1 thread/query, numpy-bit-exact rescore of
//    <=4 candidates (u64 (d,idx) key -> first-index ties).
//  vq_fixup: list B, block-per-query exact 1024-code scan.
//  vq_writeback: all queries: gather emb[idx] (float4, L2) -> coalesced z_q.

#define NUM_EMB 1024
#define EMB_DIM 32
#define HW      4096
#define BATCH   32
#define N_TOT   (BATCH * HW)  // 131072
#define NSPLIT  4
#define CODES_PER (NUM_EMB / NSPLIT)
#define MARGIN  1.0e-4f
#define CHUNK   256
#define ESTRIDE 36            // LDS row stride in shorts (bank-conflict pad)

// ws layout (all 16B aligned)
#define OFF_BQ    0u
#define OFF_EH    4096u
#define OFF_EL    69632u
#define OFF_CNT   135168u
#define OFF_CAND  659456u     // 4 ints per query
#define OFF_CTRS  2756608u    // [0]=listA count, [1]=listB count
#define OFF_LISTA 2756624u
#define OFF_LISTB 3280912u
#define WS_NEED   3805200u
#define WS_NEED_R7 (4096u + 4u * 131072u * 8u)

using bf16x8 = __attribute__((ext_vector_type(8))) short;
using bf16x4 = __attribute__((ext_vector_type(4))) short;
using f32x4  = __attribute__((ext_vector_type(4))) float;

#define REPEAT32(M) \
    M(0)  M(1)  M(2)  M(3)  M(4)  M(5)  M(6)  M(7)  \
    M(8)  M(9)  M(10) M(11) M(12) M(13) M(14) M(15) \
    M(16) M(17) M(18) M(19) M(20) M(21) M(22) M(23) \
    M(24) M(25) M(26) M(27) M(28) M(29) M(30) M(31)

__device__ __forceinline__ unsigned short bf16_rne(float x) {
    unsigned u = __float_as_uint(x);
    return (unsigned short)((u + 0x7FFFu + ((u >> 16) & 1u)) >> 16);
}

__device__ __forceinline__ float pairwise_sq32(const float* __restrict__ e) {
    float r0 = __fmul_rn(e[0], e[0]), r1 = __fmul_rn(e[1], e[1]);
    float r2 = __fmul_rn(e[2], e[2]), r3 = __fmul_rn(e[3], e[3]);
    float r4 = __fmul_rn(e[4], e[4]), r5 = __fmul_rn(e[5], e[5]);
    float r6 = __fmul_rn(e[6], e[6]), r7 = __fmul_rn(e[7], e[7]);
#pragma unroll
    for (int i = 8; i < 32; i += 8) {
        r0 = __fadd_rn(r0, __fmul_rn(e[i + 0], e[i + 0]));
        r1 = __fadd_rn(r1, __fmul_rn(e[i + 1], e[i + 1]));
        r2 = __fadd_rn(r2, __fmul_rn(e[i + 2], e[i + 2]));
        r3 = __fadd_rn(r3, __fmul_rn(e[i + 3], e[i + 3]));
        r4 = __fadd_rn(r4, __fmul_rn(e[i + 4], e[i + 4]));
        r5 = __fadd_rn(r5, __fmul_rn(e[i + 5], e[i + 5]));
        r6 = __fadd_rn(r6, __fmul_rn(e[i + 6], e[i + 6]));
        r7 = __fadd_rn(r7, __fmul_rn(e[i + 7], e[i + 7]));
    }
    return __fadd_rn(__fadd_rn(__fadd_rn(r0, r1), __fadd_rn(r2, r3)),
                     __fadd_rn(__fadd_rn(r4, r5), __fadd_rn(r6, r7)));
}

__device__ __forceinline__ void store_row16(unsigned short* dst,
                                            const unsigned short* v) {
    unsigned w[16];
#pragma unroll
    for (int i = 0; i < 16; ++i)
        w[i] = (unsigned)v[2 * i] | ((unsigned)v[2 * i + 1] << 16);
    uint4* d4 = (uint4*)dst;
    d4[0] = make_uint4(w[0], w[1], w[2], w[3]);
    d4[1] = make_uint4(w[4], w[5], w[6], w[7]);
    d4[2] = make_uint4(w[8], w[9], w[10], w[11]);
    d4[3] = make_uint4(w[12], w[13], w[14], w[15]);
}

// ---- prep_e: bq exact + (-2e) bf16 split + zero cnt/counters --------------
__global__ __launch_bounds__(256) void vq_prep_e(
        const float* __restrict__ emb, float* __restrict__ bq,
        unsigned short* __restrict__ eh, unsigned short* __restrict__ el,
        int* __restrict__ cnt, int* __restrict__ ctrs) {
    const int g = blockIdx.x * 256 + threadIdx.x;
    cnt[g] = 0;
    if (g < 2) ctrs[g] = 0;
    if (g >= NUM_EMB) return;
    const float* e = emb + g * EMB_DIM;
    bq[g] = pairwise_sq32(e);
    unsigned short h[32], l[32];
#pragma unroll
    for (int c = 0; c < 32; ++c) {
        float v = -2.0f * e[c];            // exact (power-of-2 scale)
        unsigned short hb = bf16_rne(v);
        float hf = __uint_as_float((unsigned)hb << 16);
        l[c] = bf16_rne(v - hf);
        h[c] = hb;
    }
    store_row16(eh + (size_t)g * 32, h);
    store_row16(el + (size_t)g * 32, l);
}

__device__ __forceinline__ bf16x8 lds_read8(const short* p) {
    bf16x4 a = *(const bf16x4*)p;        // 8B-aligned ds_read_b64
    bf16x4 b = *(const bf16x4*)(p + 4);
    return __builtin_shufflevector(a, b, 0, 1, 2, 3, 4, 5, 6, 7);
}

// ---- fused filter + classification ----------------------------------------
__global__ __launch_bounds__(256, 4) void vq_filter(
        const float* __restrict__ z,
        const unsigned short* __restrict__ eh,
        const unsigned short* __restrict__ el,
        const float* __restrict__ bq, int* __restrict__ cnt,
        int* __restrict__ cand, int* __restrict__ ctrs,
        int* __restrict__ listA, int* __restrict__ listB,
        float* __restrict__ out_idx) {
    __shared__ __align__(16) short seh[CHUNK * ESTRIDE];
    __shared__ __align__(16) short sel[CHUNK * ESTRIDE];
    __shared__ float sbq[CHUNK];

    const int tid  = threadIdx.x;
    const int lane = tid & 63;
    const int wv   = tid >> 6;
    const int cloc = lane & 15, quad = lane >> 4;
    const int qbase = blockIdx.x * 128 + wv * 32;

    bf16x8 azh[2], azl[2];
#pragma unroll
    for (int t = 0; t < 2; ++t) {
        const int q  = qbase + t * 16 + cloc;
        const int b  = q >> 12;
        const int hw = q & 4095;
        const float* zb = z + ((size_t)b * EMB_DIM + quad * 8) * HW + hw;
#pragma unroll
        for (int k = 0; k < 8; ++k) {
            float v = zb[(size_t)k * HW];
            unsigned short hb = bf16_rne(v);
            float hf = __uint_as_float((unsigned)hb << 16);
            azh[t][k] = (short)hb;
            azl[t][k] = (short)bf16_rne(v - hf);
        }
    }

    float m1[2][4], m2[2][4];
    int   i1[2][4];
#pragma unroll
    for (int t = 0; t < 2; ++t)
#pragma unroll
        for (int r = 0; r < 4; ++r) {
            m1[t][r] = 3.4e38f; m2[t][r] = 3.4e38f; i1[t][r] = 0;
        }

    for (int ch = 0; ch < 4; ++ch) {
        if (ch) __syncthreads();
#pragma unroll
        for (int i = 0; i < 8; ++i) {
            const int chunk = i * 256 + tid;           // 0..2047
            const int r = chunk >> 3, c = chunk & 7;   // 8 x 4-short pieces
            *(uint2*)&seh[r * ESTRIDE + c * 4] =
                *(const uint2*)(eh + (size_t)(ch * CHUNK + r) * 32 + c * 4);
            *(uint2*)&sel[r * ESTRIDE + c * 4] =
                *(const uint2*)(el + (size_t)(ch * CHUNK + r) * 32 + c * 4);
        }
        sbq[tid] = bq[ch * CHUNK + tid];
        __syncthreads();

        for (int jt = 0; jt < 16; ++jt) {
            const int row = jt * 16 + cloc;
            bf16x8 efh = lds_read8(&seh[row * ESTRIDE + quad * 8]);
            bf16x8 efl = lds_read8(&sel[row * ESTRIDE + quad * 8]);
            const float bqv = sbq[row];
            const int jts = ch * 16 + jt;
#pragma unroll
            for (int t = 0; t < 2; ++t) {
                f32x4 acc = {bqv, bqv, bqv, bqv};
                acc = __builtin_amdgcn_mfma_f32_16x16x32_bf16(azl[t], efh, acc, 0, 0, 0);
                acc = __builtin_amdgcn_mfma_f32_16x16x32_bf16(azh[t], efl, acc, 0, 0, 0);
                acc = __builtin_amdgcn_mfma_f32_16x16x32_bf16(azh[t], efh, acc, 0, 0, 0);
#pragma unroll
                for (int r = 0; r < 4; ++r) {
                    const float tt = acc[r];
                    const bool l1 = tt < m1[t][r];
                    m2[t][r] = __builtin_amdgcn_fmed3f(tt, m1[t][r], m2[t][r]);
                    m1[t][r] = fminf(m1[t][r], tt);
                    i1[t][r] = l1 ? jts : i1[t][r];
                }
            }
        }
    }

    float g[2][4];
#pragma unroll
    for (int t = 0; t < 2; ++t)
#pragma unroll
        for (int r = 0; r < 4; ++r) g[t][r] = m1[t][r];
#pragma unroll
    for (int off = 1; off < 16; off <<= 1)
#pragma unroll
        for (int t = 0; t < 2; ++t)
#pragma unroll
            for (int r = 0; r < 4; ++r)
                g[t][r] = fminf(g[t][r], __shfl_xor(g[t][r], off, 64));

    // classification: pc==1 -> done here; 2..4 -> list A; else -> list B
#pragma unroll
    for (int t = 0; t < 2; ++t)
#pragma unroll
        for (int r = 0; r < 4; ++r) {
            const float thr = g[t][r] + MARGIN;
            const int   q   = qbase + t * 16 + quad * 4 + r;
            const bool  f1  = m1[t][r] <= thr;
            const bool  f2  = m2[t][r] <= thr;
            const unsigned long long b1 = __ballot(f1);
            const unsigned long long b2 = __ballot(f2);
            const unsigned mk1 = (unsigned)(b1 >> (quad * 16)) & 0xFFFFu;
            const unsigned mk2 = (unsigned)(b2 >> (quad * 16)) & 0xFFFFu;
            const int pc  = __popc(mk1);
            const int ldr = __ffs(mk1) - 1;   // mk1 != 0 always (min lane)
            if (mk2 | (unsigned)(pc > 4)) {
                if (cloc == ldr) { int p = atomicAdd(&ctrs[1], 1); listB[p] = q; }
            } else if (pc == 1) {
                if (f1) out_idx[q] = (float)(i1[t][r] * 16 + cloc);
            } else {
                if (f1) {
                    int pos = atomicAdd(&cnt[q], 1);
                    cand[(q << 2) + pos] = i1[t][r] * 16 + cloc;
                }
                if (cloc == ldr) { int p = atomicAdd(&ctrs[0], 1); listA[p] = q; }
            }
        }
}

// ---- exact-rescore building blocks (verified numpy-fp32 chain) ------------
#define LOADZ(c) float z##c = zp[(size_t)(c) * HW];
#define Z_SQ_A()                                                              \
    float r0 = __fmul_rn(z0, z0), r1 = __fmul_rn(z1, z1);                     \
    float r2 = __fmul_rn(z2, z2), r3 = __fmul_rn(z3, z3);                     \
    float r4 = __fmul_rn(z4, z4), r5 = __fmul_rn(z5, z5);                     \
    float r6 = __fmul_rn(z6, z6), r7 = __fmul_rn(z7, z7);                     \
    r0 = __fadd_rn(r0, __fmul_rn(z8,  z8));  r0 = __fadd_rn(r0, __fmul_rn(z16, z16)); \
    r0 = __fadd_rn(r0, __fmul_rn(z24, z24));                                  \
    r1 = __fadd_rn(r1, __fmul_rn(z9,  z9));  r1 = __fadd_rn(r1, __fmul_rn(z17, z17)); \
    r1 = __fadd_rn(r1, __fmul_rn(z25, z25));                                  \
    r2 = __fadd_rn(r2, __fmul_rn(z10, z10)); r2 = __fadd_rn(r2, __fmul_rn(z18, z18)); \
    r2 = __fadd_rn(r2, __fmul_rn(z26, z26));                                  \
    r3 = __fadd_rn(r3, __fmul_rn(z11, z11)); r3 = __fadd_rn(r3, __fmul_rn(z19, z19)); \
    r3 = __fadd_rn(r3, __fmul_rn(z27, z27));                                  \
    r4 = __fadd_rn(r4, __fmul_rn(z12, z12)); r4 = __fadd_rn(r4, __fmul_rn(z20, z20)); \
    r4 = __fadd_rn(r4, __fmul_rn(z28, z28));                                  \
    r5 = __fadd_rn(r5, __fmul_rn(z13, z13)); r5 = __fadd_rn(r5, __fmul_rn(z21, z21)); \
    r5 = __fadd_rn(r5, __fmul_rn(z29, z29));                                  \
    r6 = __fadd_rn(r6, __fmul_rn(z14, z14)); r6 = __fadd_rn(r6, __fmul_rn(z22, z22)); \
    r6 = __fadd_rn(r6, __fmul_rn(z30, z30));                                  \
    r7 = __fadd_rn(r7, __fmul_rn(z15, z15)); r7 = __fadd_rn(r7, __fmul_rn(z23, z23)); \
    r7 = __fadd_rn(r7, __fmul_rn(z31, z31));                                  \
    const float a = __fadd_rn(                                                \
        __fadd_rn(__fadd_rn(r0, r1), __fadd_rn(r2, r3)),                      \
        __fadd_rn(__fadd_rn(r4, r5), __fadd_rn(r6, r7)));

#define FMA1(k) m = __fmaf_rn(z##k, e[(k)], m);
#define EXACT_KEY(jv)                                                         \
    {                                                                         \
        const float* e = emb + (size_t)(jv) * EMB_DIM;                        \
        float m = 0.0f;                                                       \
        REPEAT32(FMA1)                                                        \
        float d = __fsub_rn(__fadd_rn(a, bq[(jv)]), __fmul_rn(2.0f, m));      \
        unsigned u = __float_as_uint(d);                                      \
        u = (u & 0x80000000u) ? ~u : (u | 0x80000000u);                       \
        unsigned long long kk =                                               \
            ((unsigned long long)u << 32) | (unsigned)(jv);                   \
        if (kk < bestk) bestk = kk;                                           \
    }

// ---- rescore: compacted list A, <=4 candidates per query ------------------
__global__ __launch_bounds__(256, 2) void vq_rescore(
        const float* __restrict__ z, const float* __restrict__ emb,
        const float* __restrict__ bq, const int* __restrict__ cnt,
        const int* __restrict__ cand, const int* __restrict__ ctrs,
        const int* __restrict__ listA, float* __restrict__ out_idx) {
    const int total = ctrs[0];
    for (int i = blockIdx.x * 256 + threadIdx.x; i < total;
         i += gridDim.x * 256) {
        const int n  = listA[i];
        const int b  = n >> 12;
        const int hw = n & 4095;
        const float* zp = z + (size_t)b * EMB_DIM * HW + hw;
        REPEAT32(LOADZ)
        Z_SQ_A()
        const int c = cnt[n];
        unsigned long long bestk = ~0ull;
        for (int k = 0; k < c; ++k) { const int jv = cand[(n << 2) + k]; EXACT_KEY(jv) }
        out_idx[n] = (float)(unsigned)(bestk & 0xffffffffu);
    }
}

// ---- fixup: list B, block-per-query exact full scan -----------------------
__global__ __launch_bounds__(256) void vq_fixup(
        const float* __restrict__ z, const float* __restrict__ emb,
        const float* __restrict__ bq, const int* __restrict__ ctrs,
        const int* __restrict__ listB, float* __restrict__ out_idx) {
    __shared__ unsigned long long bs[256];
    const int tid = threadIdx.x;
    const int total = ctrs[1];

    for (int it = blockIdx.x; it < total; it += gridDim.x) {
        const int n  = listB[it];
        const int b  = n >> 12;
        const int hw = n & 4095;
        const float* zp = z + (size_t)b * EMB_DIM * HW + hw;  // broadcast
        REPEAT32(LOADZ)
        Z_SQ_A()
        unsigned long long bestk = ~0ull;
#pragma unroll
        for (int k = 0; k < 4; ++k) { const int jv = tid * 4 + k; EXACT_KEY(jv) }
        bs[tid] = bestk;
        __syncthreads();
        for (int off = 128; off > 0; off >>= 1) {
            if (tid < off && bs[tid + off] < bs[tid]) bs[tid] = bs[tid + off];
            __syncthreads();
        }
        if (tid == 0) out_idx[n] = (float)(unsigned)(bs[0] & 0xffffffffu);
        __syncthreads();
    }
}

// ---- writeback: z_q for all queries (coalesced) ---------------------------
__global__ __launch_bounds__(256) void vq_writeback(
        const float* __restrict__ emb, const float* __restrict__ out_idx,
        float* __restrict__ out_zq) {
    const int n = blockIdx.x * 256 + threadIdx.x;
    const int bidx = (int)out_idx[n];
    const int b  = n >> 12;
    const int hw = n & 4095;
    const float4* er = (const float4*)(emb + (size_t)bidx * EMB_DIM);
    float* op = out_zq + (size_t)b * EMB_DIM * HW + hw;
#pragma unroll
    for (int c4 = 0; c4 < 8; ++c4) {
        float4 v = er[c4];
        op[(size_t)(c4 * 4 + 0) * HW] = v.x;
        op[(size_t)(c4 * 4 + 1) * HW] = v.y;
        op[(size_t)(c4 * 4 + 2) * HW] = v.z;
        op[(size_t)(c4 * 4 + 3) * HW] = v.w;
    }
}

// ================== proven R7/R5 exhaustive fallback =======================
#define SCAN_GROUP4(j)                                                        \
    {                                                                         \
        const float* e = emb + (size_t)(j) * EMB_DIM;                         \
        const float bq0 = bq[(j) + 0], bq1 = bq[(j) + 1];                     \
        const float bq2 = bq[(j) + 2], bq3 = bq[(j) + 3];                     \
        float m0 = 0.0f, m1 = 0.0f, m2 = 0.0f, m3 = 0.0f;                     \
        REPEAT32(FMA_K)                                                       \
        float d0 = __fsub_rn(__fadd_rn(a, bq0), __fmul_rn(2.0f, m0));         \
        float d1 = __fsub_rn(__fadd_rn(a, bq1), __fmul_rn(2.0f, m1));         \
        float d2 = __fsub_rn(__fadd_rn(a, bq2), __fmul_rn(2.0f, m2));         \
        float d3 = __fsub_rn(__fadd_rn(a, bq3), __fmul_rn(2.0f, m3));         \
        if (d0 < best) { best = d0; bidx = (j) + 0; }                         \
        if (d1 < best) { best = d1; bidx = (j) + 1; }                         \
        if (d2 < best) { best = d2; bidx = (j) + 2; }                         \
        if (d3 < best) { best = d3; bidx = (j) + 3; }                         \
    }
#define FMA_K(k) \
        m0 = __fmaf_rn(z##k, e[0 * EMB_DIM + (k)], m0); \
        m1 = __fmaf_rn(z##k, e[1 * EMB_DIM + (k)], m1); \
        m2 = __fmaf_rn(z##k, e[2 * EMB_DIM + (k)], m2); \
        m3 = __fmaf_rn(z##k, e[3 * EMB_DIM + (k)], m3);

__global__ __launch_bounds__(256) void vq_sqnorm_kernel(
        const float* __restrict__ emb, float* __restrict__ bq) {
    int j = blockIdx.x * 256 + threadIdx.x;
    if (j < NUM_EMB) bq[j] = pairwise_sq32(emb + j * EMB_DIM);
}

__global__ __launch_bounds__(128, 4) void vq_partial_kernel(
        const float* __restrict__ z, const float* __restrict__ emb,
        const float* __restrict__ bq, unsigned long long* __restrict__ pk) {
    const int n  = blockIdx.x * 128 + threadIdx.x;
    const int b  = n >> 12;
    const int hw = n & 4095;
    const float* zp = z + (size_t)b * EMB_DIM * HW + hw;
    REPEAT32(LOADZ)
    Z_SQ_A()
    const int j0 = blockIdx.y * CODES_PER;
    float best = 3.4e38f;
    int   bidx = j0;
    for (int j = j0; j < j0 + CODES_PER; j += 4) SCAN_GROUP4(j)
    pk[(size_t)blockIdx.y * N_TOT + n] =
        ((unsigned long long)__float_as_uint(best) << 32) | (unsigned)bidx;
}

__global__ __launch_bounds__(256, 2) void vq_main_kernel(
        const float* __restrict__ z, const float* __restrict__ emb,
        const float* __restrict__ bq, float* __restrict__ out_zq,
        float* __restrict__ out_idx) {
    const int n  = blockIdx.x * 256 + threadIdx.x;
    const int b  = n >> 12;
    const int hw = n & 4095;
    const float* zp = z + (size_t)b * EMB_DIM * HW + hw;
    REPEAT32(LOADZ)
    Z_SQ_A()
    float best = 3.4e38f;
    int   bidx = 0;
    for (int j = 0; j < NUM_EMB; j += 4) SCAN_GROUP4(j)
    out_idx[n] = (float)bidx;
    const float* eb = emb + (size_t)bidx * EMB_DIM;
    float* op = out_zq + (size_t)b * EMB_DIM * HW + hw;
#pragma unroll
    for (int cc = 0; cc < EMB_DIM; ++cc) op[(size_t)cc * HW] = eb[cc];
}

__global__ __launch_bounds__(256) void vq_combine_kernel(
        const float* __restrict__ emb,
        const unsigned long long* __restrict__ pk,
        float* __restrict__ out_zq, float* __restrict__ out_idx) {
    const int n = blockIdx.x * 256 + threadIdx.x;
    unsigned long long m = pk[n];
#pragma unroll
    for (int y = 1; y < NSPLIT; ++y) {
        unsigned long long v = pk[(size_t)y * N_TOT + n];
        if (v < m) m = v;
    }
    const int bidx = (int)(unsigned)(m & 0xffffffffu);
    out_idx[n] = (float)bidx;
    const int b  = n >> 12;
    const int hw = n & 4095;
    const float* eb = emb + (size_t)bidx * EMB_DIM;
    float* op = out_zq + (size_t)b * EMB_DIM * HW + hw;
#pragma unroll
    for (int cc = 0; cc < EMB_DIM; ++cc) op[(size_t)cc * HW] = eb[cc];
}

extern "C" void kernel_launch(void* const* d_in, const int* in_sizes, int n_in,
                              void* d_out, int out_size, void* d_ws,
                              size_t ws_size, hipStream_t stream) {
    const float* z   = (const float*)d_in[0];
    const float* emb = (const float*)d_in[1];
    char* ws = (char*)d_ws;
    float* out0 = (float*)d_out;
    float* out1 = out0 + (size_t)BATCH * EMB_DIM * HW;

    if (ws_size >= WS_NEED) {
        float*          bq    = (float*)(ws + OFF_BQ);
        unsigned short* eh    = (unsigned short*)(ws + OFF_EH);
        unsigned short* el    = (unsigned short*)(ws + OFF_EL);
        int*            cnt   = (int*)(ws + OFF_CNT);
        int*            cand  = (int*)(ws + OFF_CAND);
        int*            ctrs  = (int*)(ws + OFF_CTRS);
        int*            listA = (int*)(ws + OFF_LISTA);
        int*            listB = (int*)(ws + OFF_LISTB);

        vq_prep_e<<<N_TOT / 256, 256, 0, stream>>>(emb, bq, eh, el, cnt, ctrs);
        vq_filter<<<N_TOT / 128, 256, 0, stream>>>(z, eh, el, bq, cnt, cand,
                                                   ctrs, listA, listB, out1);
        vq_rescore<<<256, 256, 0, stream>>>(z, emb, bq, cnt, cand, ctrs,
                                            listA, out1);
        vq_fixup<<<1024, 256, 0, stream>>>(z, emb, bq, ctrs, listB, out1);
        vq_writeback<<<N_TOT / 256, 256, 0, stream>>>(emb, out1, out0);
    } else if (ws_size >= WS_NEED_R7) {
        float* bq = (float*)ws;
        unsigned long long* pk = (unsigned long long*)(ws + 4096);
        vq_sqnorm_kernel<<<NUM_EMB / 256, 256, 0, stream>>>(emb, bq);
        vq_partial_kernel<<<dim3(N_TOT / 128, NSPLIT), 128, 0, stream>>>(
            z, emb, bq, pk);
        vq_combine_kernel<<<N_TOT / 256, 256, 0, stream>>>(emb, pk, out0, out1);
    } else {
        float* bq = (float*)ws;
        vq_sqnorm_kernel<<<NUM_EMB / 256, 256, 0, stream>>>(emb, bq);
        vq_main_kernel<<<N_TOT / 256, 256, 0, stream>>>(z, emb, bq, out0, out1);
    }
}

// Round 15
// 152.610 us; speedup vs baseline: 1.4203x; 1.4203x over previous
//
#include <hip/hip_runtime.h>

// VectorQuantizer: z[32,32,64,64] f32 (BCHW), emb[1024,32] f32.
// out = concat( z_q[32,32,64,64] f32 , idx[131072] stored as f32 values ).
//
// R15: R14's in-filter classification, with the single-address atomic
// hotspot removed. R14's per-leader atomicAdd(&ctrs[0/1]) (~40k serialized
// RMWs on one cacheline) stalled the filter 53->117us. Now: decisions go to
// LDS (sdest[128]), then a block-level ballot prefix-sum compacts list A/B
// with 2 atomics per block (2048 total). All scoring/margin logic is
// bit-identical to the validated R13/R14 path:
//  filter: MFMA scores (acc=bq, e pre-scaled -2), (m1,i1,m2) via med3;
//    pc==1 & no m2-in-margin -> idx written in-filter (is the argmin);
//    2..4 -> cand[4] + list A (exact rescore); else list B (full scan).
//  vq_rescore: list A, 1 thread/query, numpy-bit-exact rescore.
//  vq_fixup: list B, block-per-query exact 1024-code scan.
//  vq_writeback: gather emb[idx] -> coalesced z_q.

#define NUM_EMB 1024
#define EMB_DIM 32
#define HW      4096
#define BATCH   32
#define N_TOT   (BATCH * HW)  // 131072
#define NSPLIT  4
#define CODES_PER (NUM_EMB / NSPLIT)
#define MARGIN  1.0e-4f
#define CHUNK   256
#define ESTRIDE 36            // LDS row stride in shorts (bank-conflict pad)

// ws layout (all 16B aligned)
#define OFF_BQ    0u
#define OFF_EH    4096u
#define OFF_EL    69632u
#define OFF_CNT   135168u
#define OFF_CAND  659456u     // 4 ints per query
#define OFF_CTRS  2756608u    // [0]=listA count, [1]=listB count
#define OFF_LISTA 2756624u
#define OFF_LISTB 3280912u
#define WS_NEED   3805200u
#define WS_NEED_R7 (4096u + 4u * 131072u * 8u)

using bf16x8 = __attribute__((ext_vector_type(8))) short;
using bf16x4 = __attribute__((ext_vector_type(4))) short;
using f32x4  = __attribute__((ext_vector_type(4))) float;

#define REPEAT32(M) \
    M(0)  M(1)  M(2)  M(3)  M(4)  M(5)  M(6)  M(7)  \
    M(8)  M(9)  M(10) M(11) M(12) M(13) M(14) M(15) \
    M(16) M(17) M(18) M(19) M(20) M(21) M(22) M(23) \
    M(24) M(25) M(26) M(27) M(28) M(29) M(30) M(31)

__device__ __forceinline__ unsigned short bf16_rne(float x) {
    unsigned u = __float_as_uint(x);
    return (unsigned short)((u + 0x7FFFu + ((u >> 16) & 1u)) >> 16);
}

__device__ __forceinline__ float pairwise_sq32(const float* __restrict__ e) {
    float r0 = __fmul_rn(e[0], e[0]), r1 = __fmul_rn(e[1], e[1]);
    float r2 = __fmul_rn(e[2], e[2]), r3 = __fmul_rn(e[3], e[3]);
    float r4 = __fmul_rn(e[4], e[4]), r5 = __fmul_rn(e[5], e[5]);
    float r6 = __fmul_rn(e[6], e[6]), r7 = __fmul_rn(e[7], e[7]);
#pragma unroll
    for (int i = 8; i < 32; i += 8) {
        r0 = __fadd_rn(r0, __fmul_rn(e[i + 0], e[i + 0]));
        r1 = __fadd_rn(r1, __fmul_rn(e[i + 1], e[i + 1]));
        r2 = __fadd_rn(r2, __fmul_rn(e[i + 2], e[i + 2]));
        r3 = __fadd_rn(r3, __fmul_rn(e[i + 3], e[i + 3]));
        r4 = __fadd_rn(r4, __fmul_rn(e[i + 4], e[i + 4]));
        r5 = __fadd_rn(r5, __fmul_rn(e[i + 5], e[i + 5]));
        r6 = __fadd_rn(r6, __fmul_rn(e[i + 6], e[i + 6]));
        r7 = __fadd_rn(r7, __fmul_rn(e[i + 7], e[i + 7]));
    }
    return __fadd_rn(__fadd_rn(__fadd_rn(r0, r1), __fadd_rn(r2, r3)),
                     __fadd_rn(__fadd_rn(r4, r5), __fadd_rn(r6, r7)));
}

__device__ __forceinline__ void store_row16(unsigned short* dst,
                                            const unsigned short* v) {
    unsigned w[16];
#pragma unroll
    for (int i = 0; i < 16; ++i)
        w[i] = (unsigned)v[2 * i] | ((unsigned)v[2 * i + 1] << 16);
    uint4* d4 = (uint4*)dst;
    d4[0] = make_uint4(w[0], w[1], w[2], w[3]);
    d4[1] = make_uint4(w[4], w[5], w[6], w[7]);
    d4[2] = make_uint4(w[8], w[9], w[10], w[11]);
    d4[3] = make_uint4(w[12], w[13], w[14], w[15]);
}

// ---- prep_e: bq exact + (-2e) bf16 split + zero cnt/counters --------------
__global__ __launch_bounds__(256) void vq_prep_e(
        const float* __restrict__ emb, float* __restrict__ bq,
        unsigned short* __restrict__ eh, unsigned short* __restrict__ el,
        int* __restrict__ cnt, int* __restrict__ ctrs) {
    const int g = blockIdx.x * 256 + threadIdx.x;
    cnt[g] = 0;
    if (g < 2) ctrs[g] = 0;
    if (g >= NUM_EMB) return;
    const float* e = emb + g * EMB_DIM;
    bq[g] = pairwise_sq32(e);
    unsigned short h[32], l[32];
#pragma unroll
    for (int c = 0; c < 32; ++c) {
        float v = -2.0f * e[c];            // exact (power-of-2 scale)
        unsigned short hb = bf16_rne(v);
        float hf = __uint_as_float((unsigned)hb << 16);
        l[c] = bf16_rne(v - hf);
        h[c] = hb;
    }
    store_row16(eh + (size_t)g * 32, h);
    store_row16(el + (size_t)g * 32, l);
}

__device__ __forceinline__ bf16x8 lds_read8(const short* p) {
    bf16x4 a = *(const bf16x4*)p;        // 8B-aligned ds_read_b64
    bf16x4 b = *(const bf16x4*)(p + 4);
    return __builtin_shufflevector(a, b, 0, 1, 2, 3, 4, 5, 6, 7);
}

// ---- fused filter + classification + block-compacted lists ----------------
__global__ __launch_bounds__(256, 4) void vq_filter(
        const float* __restrict__ z,
        const unsigned short* __restrict__ eh,
        const unsigned short* __restrict__ el,
        const float* __restrict__ bq, int* __restrict__ cnt,
        int* __restrict__ cand, int* __restrict__ ctrs,
        int* __restrict__ listA, int* __restrict__ listB,
        float* __restrict__ out_idx) {
    __shared__ __align__(16) short seh[CHUNK * ESTRIDE];
    __shared__ __align__(16) short sel[CHUNK * ESTRIDE];
    __shared__ float sbq[CHUNK];
    __shared__ int   sdest[128];
    __shared__ int   swt[4];     // [w*2+0]=A count wave w, [w*2+1]=B count
    __shared__ int   sbase[2];

    const int tid  = threadIdx.x;
    const int lane = tid & 63;
    const int wv   = tid >> 6;
    const int cloc = lane & 15, quad = lane >> 4;
    const int qbase = blockIdx.x * 128 + wv * 32;

    bf16x8 azh[2], azl[2];
#pragma unroll
    for (int t = 0; t < 2; ++t) {
        const int q  = qbase + t * 16 + cloc;
        const int b  = q >> 12;
        const int hw = q & 4095;
        const float* zb = z + ((size_t)b * EMB_DIM + quad * 8) * HW + hw;
#pragma unroll
        for (int k = 0; k < 8; ++k) {
            float v = zb[(size_t)k * HW];
            unsigned short hb = bf16_rne(v);
            float hf = __uint_as_float((unsigned)hb << 16);
            azh[t][k] = (short)hb;
            azl[t][k] = (short)bf16_rne(v - hf);
        }
    }

    float m1[2][4], m2[2][4];
    int   i1[2][4];
#pragma unroll
    for (int t = 0; t < 2; ++t)
#pragma unroll
        for (int r = 0; r < 4; ++r) {
            m1[t][r] = 3.4e38f; m2[t][r] = 3.4e38f; i1[t][r] = 0;
        }

    for (int ch = 0; ch < 4; ++ch) {
        if (ch) __syncthreads();
#pragma unroll
        for (int i = 0; i < 8; ++i) {
            const int chunk = i * 256 + tid;           // 0..2047
            const int r = chunk >> 3, c = chunk & 7;   // 8 x 4-short pieces
            *(uint2*)&seh[r * ESTRIDE + c * 4] =
                *(const uint2*)(eh + (size_t)(ch * CHUNK + r) * 32 + c * 4);
            *(uint2*)&sel[r * ESTRIDE + c * 4] =
                *(const uint2*)(el + (size_t)(ch * CHUNK + r) * 32 + c * 4);
        }
        sbq[tid] = bq[ch * CHUNK + tid];
        __syncthreads();

        for (int jt = 0; jt < 16; ++jt) {
            const int row = jt * 16 + cloc;
            bf16x8 efh = lds_read8(&seh[row * ESTRIDE + quad * 8]);
            bf16x8 efl = lds_read8(&sel[row * ESTRIDE + quad * 8]);
            const float bqv = sbq[row];
            const int jts = ch * 16 + jt;
#pragma unroll
            for (int t = 0; t < 2; ++t) {
                f32x4 acc = {bqv, bqv, bqv, bqv};
                acc = __builtin_amdgcn_mfma_f32_16x16x32_bf16(azl[t], efh, acc, 0, 0, 0);
                acc = __builtin_amdgcn_mfma_f32_16x16x32_bf16(azh[t], efl, acc, 0, 0, 0);
                acc = __builtin_amdgcn_mfma_f32_16x16x32_bf16(azh[t], efh, acc, 0, 0, 0);
#pragma unroll
                for (int r = 0; r < 4; ++r) {
                    const float tt = acc[r];
                    const bool l1 = tt < m1[t][r];
                    m2[t][r] = __builtin_amdgcn_fmed3f(tt, m1[t][r], m2[t][r]);
                    m1[t][r] = fminf(m1[t][r], tt);
                    i1[t][r] = l1 ? jts : i1[t][r];
                }
            }
        }
    }

    float g[2][4];
#pragma unroll
    for (int t = 0; t < 2; ++t)
#pragma unroll
        for (int r = 0; r < 4; ++r) g[t][r] = m1[t][r];
#pragma unroll
    for (int off = 1; off < 16; off <<= 1)
#pragma unroll
        for (int t = 0; t < 2; ++t)
#pragma unroll
            for (int r = 0; r < 4; ++r)
                g[t][r] = fminf(g[t][r], __shfl_xor(g[t][r], off, 64));

    // classification -> LDS (exactly one writer per query: the leader lane)
#pragma unroll
    for (int t = 0; t < 2; ++t)
#pragma unroll
        for (int r = 0; r < 4; ++r) {
            const float thr = g[t][r] + MARGIN;
            const int   q   = qbase + t * 16 + quad * 4 + r;
            const int   ql  = wv * 32 + t * 16 + quad * 4 + r;  // 0..127
            const bool  f1  = m1[t][r] <= thr;
            const bool  f2  = m2[t][r] <= thr;
            const unsigned long long b1 = __ballot(f1);
            const unsigned long long b2 = __ballot(f2);
            const unsigned mk1 = (unsigned)(b1 >> (quad * 16)) & 0xFFFFu;
            const unsigned mk2 = (unsigned)(b2 >> (quad * 16)) & 0xFFFFu;
            const int pc  = __popc(mk1);
            const int ldr = __ffs(mk1) - 1;   // mk1 != 0 (global-min lane)
            if (mk2 | (unsigned)(pc > 4)) {
                if (cloc == ldr) sdest[ql] = 2;
            } else if (pc == 1) {
                if (cloc == ldr) {            // the single f1 lane == leader
                    out_idx[q] = (float)(i1[t][r] * 16 + cloc);
                    sdest[ql] = 0;
                }
            } else {
                if (f1) {
                    int pos = atomicAdd(&cnt[q], 1);   // distinct addresses
                    cand[(q << 2) + pos] = i1[t][r] * 16 + cloc;
                }
                if (cloc == ldr) sdest[ql] = 1;
            }
        }
    __syncthreads();

    // block-level compaction: 2 global atomics per block (was ~40/block)
    int d = 0, preA = 0, preB = 0;
    if (tid < 128) {
        d = sdest[tid];
        const unsigned long long mA = __ballot(d == 1);
        const unsigned long long mB = __ballot(d == 2);
        const unsigned long long lm = (1ull << lane) - 1ull;
        preA = (int)__popcll(mA & lm);
        preB = (int)__popcll(mB & lm);
        if (lane == 0) {
            swt[(tid >> 6) * 2 + 0] = (int)__popcll(mA);
            swt[(tid >> 6) * 2 + 1] = (int)__popcll(mB);
        }
    }
    __syncthreads();
    if (tid == 0) {
        const int tA = swt[0] + swt[2];
        const int tB = swt[1] + swt[3];
        sbase[0] = tA ? atomicAdd(&ctrs[0], tA) : 0;
        sbase[1] = tB ? atomicAdd(&ctrs[1], tB) : 0;
    }
    __syncthreads();
    if (tid < 128) {
        const int woff = tid >> 6;        // 0 or 1
        if (d == 1)
            listA[sbase[0] + (woff ? swt[0] : 0) + preA] =
                blockIdx.x * 128 + tid;
        if (d == 2)
            listB[sbase[1] + (woff ? swt[1] : 0) + preB] =
                blockIdx.x * 128 + tid;
    }
}

// ---- exact-rescore building blocks (verified numpy-fp32 chain) ------------
#define LOADZ(c) float z##c = zp[(size_t)(c) * HW];
#define Z_SQ_A()                                                              \
    float r0 = __fmul_rn(z0, z0), r1 = __fmul_rn(z1, z1);                     \
    float r2 = __fmul_rn(z2, z2), r3 = __fmul_rn(z3, z3);                     \
    float r4 = __fmul_rn(z4, z4), r5 = __fmul_rn(z5, z5);                     \
    float r6 = __fmul_rn(z6, z6), r7 = __fmul_rn(z7, z7);                     \
    r0 = __fadd_rn(r0, __fmul_rn(z8,  z8));  r0 = __fadd_rn(r0, __fmul_rn(z16, z16)); \
    r0 = __fadd_rn(r0, __fmul_rn(z24, z24));                                  \
    r1 = __fadd_rn(r1, __fmul_rn(z9,  z9));  r1 = __fadd_rn(r1, __fmul_rn(z17, z17)); \
    r1 = __fadd_rn(r1, __fmul_rn(z25, z25));                                  \
    r2 = __fadd_rn(r2, __fmul_rn(z10, z10)); r2 = __fadd_rn(r2, __fmul_rn(z18, z18)); \
    r2 = __fadd_rn(r2, __fmul_rn(z26, z26));                                  \
    r3 = __fadd_rn(r3, __fmul_rn(z11, z11)); r3 = __fadd_rn(r3, __fmul_rn(z19, z19)); \
    r3 = __fadd_rn(r3, __fmul_rn(z27, z27));                                  \
    r4 = __fadd_rn(r4, __fmul_rn(z12, z12)); r4 = __fadd_rn(r4, __fmul_rn(z20, z20)); \
    r4 = __fadd_rn(r4, __fmul_rn(z28, z28));                                  \
    r5 = __fadd_rn(r5, __fmul_rn(z13, z13)); r5 = __fadd_rn(r5, __fmul_rn(z21, z21)); \
    r5 = __fadd_rn(r5, __fmul_rn(z29, z29));                                  \
    r6 = __fadd_rn(r6, __fmul_rn(z14, z14)); r6 = __fadd_rn(r6, __fmul_rn(z22, z22)); \
    r6 = __fadd_rn(r6, __fmul_rn(z30, z30));                                  \
    r7 = __fadd_rn(r7, __fmul_rn(z15, z15)); r7 = __fadd_rn(r7, __fmul_rn(z23, z23)); \
    r7 = __fadd_rn(r7, __fmul_rn(z31, z31));                                  \
    const float a = __fadd_rn(                                                \
        __fadd_rn(__fadd_rn(r0, r1), __fadd_rn(r2, r3)),                      \
        __fadd_rn(__fadd_rn(r4, r5), __fadd_rn(r6, r7)));

#define FMA1(k) m = __fmaf_rn(z##k, e[(k)], m);
#define EXACT_KEY(jv)                                                         \
    {                                                                         \
        const float* e = emb + (size_t)(jv) * EMB_DIM;                        \
        float m = 0.0f;                                                       \
        REPEAT32(FMA1)                                                        \
        float d = __fsub_rn(__fadd_rn(a, bq[(jv)]), __fmul_rn(2.0f, m));      \
        unsigned u = __float_as_uint(d);                                      \
        u = (u & 0x80000000u) ? ~u : (u | 0x80000000u);                       \
        unsigned long long kk =                                               \
            ((unsigned long long)u << 32) | (unsigned)(jv);                   \
        if (kk < bestk) bestk = kk;                                           \
    }

// ---- rescore: compacted list A, <=4 candidates per query ------------------
__global__ __launch_bounds__(256, 2) void vq_rescore(
        const float* __restrict__ z, const float* __restrict__ emb,
        const float* __restrict__ bq, const int* __restrict__ cnt,
        const int* __restrict__ cand, const int* __restrict__ ctrs,
        const int* __restrict__ listA, float* __restrict__ out_idx) {
    const int total = ctrs[0];
    for (int i = blockIdx.x * 256 + threadIdx.x; i < total;
         i += gridDim.x * 256) {
        const int n  = listA[i];
        const int b  = n >> 12;
        const int hw = n & 4095;
        const float* zp = z + (size_t)b * EMB_DIM * HW + hw;
        REPEAT32(LOADZ)
        Z_SQ_A()
        const int c = cnt[n];
        unsigned long long bestk = ~0ull;
        for (int k = 0; k < c; ++k) { const int jv = cand[(n << 2) + k]; EXACT_KEY(jv) }
        out_idx[n] = (float)(unsigned)(bestk & 0xffffffffu);
    }
}

// ---- fixup: list B, block-per-query exact full scan -----------------------
__global__ __launch_bounds__(256) void vq_fixup(
        const float* __restrict__ z, const float* __restrict__ emb,
        const float* __restrict__ bq, const int* __restrict__ ctrs,
        const int* __restrict__ listB, float* __restrict__ out_idx) {
    __shared__ unsigned long long bs[256];
    const int tid = threadIdx.x;
    const int total = ctrs[1];

    for (int it = blockIdx.x; it < total; it += gridDim.x) {
        const int n  = listB[it];
        const int b  = n >> 12;
        const int hw = n & 4095;
        const float* zp = z + (size_t)b * EMB_DIM * HW + hw;  // broadcast
        REPEAT32(LOADZ)
        Z_SQ_A()
        unsigned long long bestk = ~0ull;
#pragma unroll
        for (int k = 0; k < 4; ++k) { const int jv = tid * 4 + k; EXACT_KEY(jv) }
        bs[tid] = bestk;
        __syncthreads();
        for (int off = 128; off > 0; off >>= 1) {
            if (tid < off && bs[tid + off] < bs[tid]) bs[tid] = bs[tid + off];
            __syncthreads();
        }
        if (tid == 0) out_idx[n] = (float)(unsigned)(bs[0] & 0xffffffffu);
        __syncthreads();
    }
}

// ---- writeback: z_q for all queries (coalesced) ---------------------------
__global__ __launch_bounds__(256) void vq_writeback(
        const float* __restrict__ emb, const float* __restrict__ out_idx,
        float* __restrict__ out_zq) {
    const int n = blockIdx.x * 256 + threadIdx.x;
    const int bidx = (int)out_idx[n];
    const int b  = n >> 12;
    const int hw = n & 4095;
    const float4* er = (const float4*)(emb + (size_t)bidx * EMB_DIM);
    float* op = out_zq + (size_t)b * EMB_DIM * HW + hw;
#pragma unroll
    for (int c4 = 0; c4 < 8; ++c4) {
        float4 v = er[c4];
        op[(size_t)(c4 * 4 + 0) * HW] = v.x;
        op[(size_t)(c4 * 4 + 1) * HW] = v.y;
        op[(size_t)(c4 * 4 + 2) * HW] = v.z;
        op[(size_t)(c4 * 4 + 3) * HW] = v.w;
    }
}

// ================== proven R7/R5 exhaustive fallback =======================
#define SCAN_GROUP4(j)                                                        \
    {                                                                         \
        const float* e = emb + (size_t)(j) * EMB_DIM;                         \
        const float bq0 = bq[(j) + 0], bq1 = bq[(j) + 1];                     \
        const float bq2 = bq[(j) + 2], bq3 = bq[(j) + 3];                     \
        float m0 = 0.0f, m1 = 0.0f, m2 = 0.0f, m3 = 0.0f;                     \
        REPEAT32(FMA_K)                                                       \
        float d0 = __fsub_rn(__fadd_rn(a, bq0), __fmul_rn(2.0f, m0));         \
        float d1 = __fsub_rn(__fadd_rn(a, bq1), __fmul_rn(2.0f, m1));         \
        float d2 = __fsub_rn(__fadd_rn(a, bq2), __fmul_rn(2.0f, m2));         \
        float d3 = __fsub_rn(__fadd_rn(a, bq3), __fmul_rn(2.0f, m3));         \
        if (d0 < best) { best = d0; bidx = (j) + 0; }                         \
        if (d1 < best) { best = d1; bidx = (j) + 1; }                         \
        if (d2 < best) { best = d2; bidx = (j) + 2; }                         \
        if (d3 < best) { best = d3; bidx = (j) + 3; }                         \
    }
#define FMA_K(k) \
        m0 = __fmaf_rn(z##k, e[0 * EMB_DIM + (k)], m0); \
        m1 = __fmaf_rn(z##k, e[1 * EMB_DIM + (k)], m1); \
        m2 = __fmaf_rn(z##k, e[2 * EMB_DIM + (k)], m2); \
        m3 = __fmaf_rn(z##k, e[3 * EMB_DIM + (k)], m3);

__global__ __launch_bounds__(256) void vq_sqnorm_kernel(
        const float* __restrict__ emb, float* __restrict__ bq) {
    int j = blockIdx.x * 256 + threadIdx.x;
    if (j < NUM_EMB) bq[j] = pairwise_sq32(emb + j * EMB_DIM);
}

__global__ __launch_bounds__(128, 4) void vq_partial_kernel(
        const float* __restrict__ z, const float* __restrict__ emb,
        const float* __restrict__ bq, unsigned long long* __restrict__ pk) {
    const int n  = blockIdx.x * 128 + threadIdx.x;
    const int b  = n >> 12;
    const int hw = n & 4095;
    const float* zp = z + (size_t)b * EMB_DIM * HW + hw;
    REPEAT32(LOADZ)
    Z_SQ_A()
    const int j0 = blockIdx.y * CODES_PER;
    float best = 3.4e38f;
    int   bidx = j0;
    for (int j = j0; j < j0 + CODES_PER; j += 4) SCAN_GROUP4(j)
    pk[(size_t)blockIdx.y * N_TOT + n] =
        ((unsigned long long)__float_as_uint(best) << 32) | (unsigned)bidx;
}

__global__ __launch_bounds__(256, 2) void vq_main_kernel(
        const float* __restrict__ z, const float* __restrict__ emb,
        const float* __restrict__ bq, float* __restrict__ out_zq,
        float* __restrict__ out_idx) {
    const int n  = blockIdx.x * 256 + threadIdx.x;
    const int b  = n >> 12;
    const int hw = n & 4095;
    const float* zp = z + (size_t)b * EMB_DIM * HW + hw;
    REPEAT32(LOADZ)
    Z_SQ_A()
    float best = 3.4e38f;
    int   bidx = 0;
    for (int j = 0; j < NUM_EMB; j += 4) SCAN_GROUP4(j)
    out_idx[n] = (float)bidx;
    const float* eb = emb + (size_t)bidx * EMB_DIM;
    float* op = out_zq + (size_t)b * EMB_DIM * HW + hw;
#pragma unroll
    for (int cc = 0; cc < EMB_DIM; ++cc) op[(size_t)cc * HW] = eb[cc];
}

__global__ __launch_bounds__(256) void vq_combine_kernel(
        const float* __restrict__ emb,
        const unsigned long long* __restrict__ pk,
        float* __restrict__ out_zq, float* __restrict__ out_idx) {
    const int n = blockIdx.x * 256 + threadIdx.x;
    unsigned long long m = pk[n];
#pragma unroll
    for (int y = 1; y < NSPLIT; ++y) {
        unsigned long long v = pk[(size_t)y * N_TOT + n];
        if (v < m) m = v;
    }
    const int bidx = (int)(unsigned)(m & 0xffffffffu);
    out_idx[n] = (float)bidx;
    const int b  = n >> 12;
    const int hw = n & 4095;
    const float* eb = emb + (size_t)bidx * EMB_DIM;
    float* op = out_zq + (size_t)b * EMB_DIM * HW + hw;
#pragma unroll
    for (int cc = 0; cc < EMB_DIM; ++cc) op[(size_t)cc * HW] = eb[cc];
}

extern "C" void kernel_launch(void* const* d_in, const int* in_sizes, int n_in,
                              void* d_out, int out_size, void* d_ws,
                              size_t ws_size, hipStream_t stream) {
    const float* z   = (const float*)d_in[0];
    const float* emb = (const float*)d_in[1];
    char* ws = (char*)d_ws;
    float* out0 = (float*)d_out;
    float* out1 = out0 + (size_t)BATCH * EMB_DIM * HW;

    if (ws_size >= WS_NEED) {
        float*          bq    = (float*)(ws + OFF_BQ);
        unsigned short* eh    = (unsigned short*)(ws + OFF_EH);
        unsigned short* el    = (unsigned short*)(ws + OFF_EL);
        int*            cnt   = (int*)(ws + OFF_CNT);
        int*            cand  = (int*)(ws + OFF_CAND);
        int*            ctrs  = (int*)(ws + OFF_CTRS);
        int*            listA = (int*)(ws + OFF_LISTA);
        int*            listB = (int*)(ws + OFF_LISTB);

        vq_prep_e<<<N_TOT / 256, 256, 0, stream>>>(emb, bq, eh, el, cnt, ctrs);
        vq_filter<<<N_TOT / 128, 256, 0, stream>>>(z, eh, el, bq, cnt, cand,
                                                   ctrs, listA, listB, out1);
        vq_rescore<<<256, 256, 0, stream>>>(z, emb, bq, cnt, cand, ctrs,
                                            listA, out1);
        vq_fixup<<<1024, 256, 0, stream>>>(z, emb, bq, ctrs, listB, out1);
        vq_writeback<<<N_TOT / 256, 256, 0, stream>>>(emb, out1, out0);
    } else if (ws_size >= WS_NEED_R7) {
        float* bq = (float*)ws;
        unsigned long long* pk = (unsigned long long*)(ws + 4096);
        vq_sqnorm_kernel<<<NUM_EMB / 256, 256, 0, stream>>>(emb, bq);
        vq_partial_kernel<<<dim3(N_TOT / 128, NSPLIT), 128, 0, stream>>>(
            z, emb, bq, pk);
        vq_combine_kernel<<<N_TOT / 256, 256, 0, stream>>>(emb, pk, out0, out1);
    } else {
        float* bq = (float*)ws;
        vq_sqnorm_kernel<<<NUM_EMB / 256, 256, 0, stream>>>(emb, bq);
        vq_main_kernel<<<N_TOT / 256, 256, 0, stream>>>(z, emb, bq, out0, out1);
    }
}

// Round 16
// 130.139 us; speedup vs baseline: 1.6655x; 1.1727x over previous
//
#include <hip/hip_runtime.h>

// VectorQuantizer: z[32,32,64,64] f32 (BCHW), emb[1024,32] f32.
// out = concat( z_q[32,32,64,64] f32 , idx[131072] stored as f32 values ).
//
// R16: single mega-filter. After the MFMA scan (acc=bq, e pre-scaled -2,
// (m1,i1,m2) via med3 - validated R13..R15 logic), the block:
//   1. parks each lane's z floats in LDS (reusing the staging region - the
//      scan is complete; barrier-separated) and classifies each query via
//      ballots with NO atomics: candidates -> scand[ql][4] by ballot-prefix
//      slot, pc -> sdest[ql]; pc>4 or 2nd-best-in-margin -> listB
//      (1 atomic per block).
//   2. 128 threads: pc==1 -> idx = the candidate (proof: it is the argmin);
//      pc 2..4 -> numpy-bit-exact rescore in-block (z from LDS, e/bq L2,
//      u64 (d,idx) key -> np.argmin first-index ties).
//   3. writes idx + z_q coalesced for all non-B queries.
// vq_fixup: listB block-per-query exact 1024-code scan + idx + z_q.
// 3 kernels total (prep_e is 4 blocks).

#define NUM_EMB 1024
#define EMB_DIM 32
#define HW      4096
#define BATCH   32
#define N_TOT   (BATCH * HW)  // 131072
#define NSPLIT  4
#define CODES_PER (NUM_EMB / NSPLIT)
#define MARGIN  1.0e-4f
#define CHUNK   256
#define ESTRIDE 36            // LDS row stride in shorts (bank-conflict pad)

// ws layout
#define OFF_BQ    0u
#define OFF_EH    4096u
#define OFF_EL    69632u
#define OFF_CTRS  135168u     // [1]=listB count ([0] unused)
#define OFF_LISTB 135184u
#define WS_NEED   659472u
#define WS_NEED_R7 (4096u + 4u * 131072u * 8u)

using bf16x8 = __attribute__((ext_vector_type(8))) short;
using bf16x4 = __attribute__((ext_vector_type(4))) short;
using f32x4  = __attribute__((ext_vector_type(4))) float;

#define REPEAT32(M) \
    M(0)  M(1)  M(2)  M(3)  M(4)  M(5)  M(6)  M(7)  \
    M(8)  M(9)  M(10) M(11) M(12) M(13) M(14) M(15) \
    M(16) M(17) M(18) M(19) M(20) M(21) M(22) M(23) \
    M(24) M(25) M(26) M(27) M(28) M(29) M(30) M(31)

__device__ __forceinline__ unsigned short bf16_rne(float x) {
    unsigned u = __float_as_uint(x);
    return (unsigned short)((u + 0x7FFFu + ((u >> 16) & 1u)) >> 16);
}

__device__ __forceinline__ float pairwise_sq32(const float* __restrict__ e) {
    float r0 = __fmul_rn(e[0], e[0]), r1 = __fmul_rn(e[1], e[1]);
    float r2 = __fmul_rn(e[2], e[2]), r3 = __fmul_rn(e[3], e[3]);
    float r4 = __fmul_rn(e[4], e[4]), r5 = __fmul_rn(e[5], e[5]);
    float r6 = __fmul_rn(e[6], e[6]), r7 = __fmul_rn(e[7], e[7]);
#pragma unroll
    for (int i = 8; i < 32; i += 8) {
        r0 = __fadd_rn(r0, __fmul_rn(e[i + 0], e[i + 0]));
        r1 = __fadd_rn(r1, __fmul_rn(e[i + 1], e[i + 1]));
        r2 = __fadd_rn(r2, __fmul_rn(e[i + 2], e[i + 2]));
        r3 = __fadd_rn(r3, __fmul_rn(e[i + 3], e[i + 3]));
        r4 = __fadd_rn(r4, __fmul_rn(e[i + 4], e[i + 4]));
        r5 = __fadd_rn(r5, __fmul_rn(e[i + 5], e[i + 5]));
        r6 = __fadd_rn(r6, __fmul_rn(e[i + 6], e[i + 6]));
        r7 = __fadd_rn(r7, __fmul_rn(e[i + 7], e[i + 7]));
    }
    return __fadd_rn(__fadd_rn(__fadd_rn(r0, r1), __fadd_rn(r2, r3)),
                     __fadd_rn(__fadd_rn(r4, r5), __fadd_rn(r6, r7)));
}

__device__ __forceinline__ void store_row16(unsigned short* dst,
                                            const unsigned short* v) {
    unsigned w[16];
#pragma unroll
    for (int i = 0; i < 16; ++i)
        w[i] = (unsigned)v[2 * i] | ((unsigned)v[2 * i + 1] << 16);
    uint4* d4 = (uint4*)dst;
    d4[0] = make_uint4(w[0], w[1], w[2], w[3]);
    d4[1] = make_uint4(w[4], w[5], w[6], w[7]);
    d4[2] = make_uint4(w[8], w[9], w[10], w[11]);
    d4[3] = make_uint4(w[12], w[13], w[14], w[15]);
}

// ---- prep_e: bq exact + (-2e) bf16 split + zero ctrs ----------------------
__global__ __launch_bounds__(256) void vq_prep_e(
        const float* __restrict__ emb, float* __restrict__ bq,
        unsigned short* __restrict__ eh, unsigned short* __restrict__ el,
        int* __restrict__ ctrs) {
    const int g = blockIdx.x * 256 + threadIdx.x;
    if (g < 2) ctrs[g] = 0;
    if (g >= NUM_EMB) return;
    const float* e = emb + g * EMB_DIM;
    bq[g] = pairwise_sq32(e);
    unsigned short h[32], l[32];
#pragma unroll
    for (int c = 0; c < 32; ++c) {
        float v = -2.0f * e[c];            // exact (power-of-2 scale)
        unsigned short hb = bf16_rne(v);
        float hf = __uint_as_float((unsigned)hb << 16);
        l[c] = bf16_rne(v - hf);
        h[c] = hb;
    }
    store_row16(eh + (size_t)g * 32, h);
    store_row16(el + (size_t)g * 32, l);
}

__device__ __forceinline__ bf16x8 lds_read8(const short* p) {
    bf16x4 a = *(const bf16x4*)p;        // 8B-aligned ds_read_b64
    bf16x4 b = *(const bf16x4*)(p + 4);
    return __builtin_shufflevector(a, b, 0, 1, 2, 3, 4, 5, 6, 7);
}

// ---- exact-rescore building blocks (verified numpy-fp32 chain) ------------
#define LOADZ(c) float z##c = zp[(size_t)(c) * HW];
#define Z_SQ_A()                                                              \
    float r0 = __fmul_rn(z0, z0), r1 = __fmul_rn(z1, z1);                     \
    float r2 = __fmul_rn(z2, z2), r3 = __fmul_rn(z3, z3);                     \
    float r4 = __fmul_rn(z4, z4), r5 = __fmul_rn(z5, z5);                     \
    float r6 = __fmul_rn(z6, z6), r7 = __fmul_rn(z7, z7);                     \
    r0 = __fadd_rn(r0, __fmul_rn(z8,  z8));  r0 = __fadd_rn(r0, __fmul_rn(z16, z16)); \
    r0 = __fadd_rn(r0, __fmul_rn(z24, z24));                                  \
    r1 = __fadd_rn(r1, __fmul_rn(z9,  z9));  r1 = __fadd_rn(r1, __fmul_rn(z17, z17)); \
    r1 = __fadd_rn(r1, __fmul_rn(z25, z25));                                  \
    r2 = __fadd_rn(r2, __fmul_rn(z10, z10)); r2 = __fadd_rn(r2, __fmul_rn(z18, z18)); \
    r2 = __fadd_rn(r2, __fmul_rn(z26, z26));                                  \
    r3 = __fadd_rn(r3, __fmul_rn(z11, z11)); r3 = __fadd_rn(r3, __fmul_rn(z19, z19)); \
    r3 = __fadd_rn(r3, __fmul_rn(z27, z27));                                  \
    r4 = __fadd_rn(r4, __fmul_rn(z12, z12)); r4 = __fadd_rn(r4, __fmul_rn(z20, z20)); \
    r4 = __fadd_rn(r4, __fmul_rn(z28, z28));                                  \
    r5 = __fadd_rn(r5, __fmul_rn(z13, z13)); r5 = __fadd_rn(r5, __fmul_rn(z21, z21)); \
    r5 = __fadd_rn(r5, __fmul_rn(z29, z29));                                  \
    r6 = __fadd_rn(r6, __fmul_rn(z14, z14)); r6 = __fadd_rn(r6, __fmul_rn(z22, z22)); \
    r6 = __fadd_rn(r6, __fmul_rn(z30, z30));                                  \
    r7 = __fadd_rn(r7, __fmul_rn(z15, z15)); r7 = __fadd_rn(r7, __fmul_rn(z23, z23)); \
    r7 = __fadd_rn(r7, __fmul_rn(z31, z31));                                  \
    const float a = __fadd_rn(                                                \
        __fadd_rn(__fadd_rn(r0, r1), __fadd_rn(r2, r3)),                      \
        __fadd_rn(__fadd_rn(r4, r5), __fadd_rn(r6, r7)));

#define FMA1(k) m = __fmaf_rn(z##k, e[(k)], m);
#define EXACT_KEY(jv)                                                         \
    {                                                                         \
        const float* e = emb + (size_t)(jv) * EMB_DIM;                        \
        float m = 0.0f;                                                       \
        REPEAT32(FMA1)                                                        \
        float d = __fsub_rn(__fadd_rn(a, bq[(jv)]), __fmul_rn(2.0f, m));      \
        unsigned u = __float_as_uint(d);                                      \
        u = (u & 0x80000000u) ? ~u : (u | 0x80000000u);                       \
        unsigned long long kk =                                               \
            ((unsigned long long)u << 32) | (unsigned)(jv);                   \
        if (kk < bestk) bestk = kk;                                           \
    }

// ---- mega filter: scan + classify + rescore + writeback -------------------
// Block = 256 thr = 4 waves; wave: 32 queries (2 tiles); block: 128 queries.
// LDS phase 1: seh/sel/sbq staging. Phase 2 (aliased): sz/scand/sdest/sidx.
__global__ __launch_bounds__(256, 4) void vq_filter(
        const float* __restrict__ z, const float* __restrict__ emb,
        const unsigned short* __restrict__ eh,
        const unsigned short* __restrict__ el,
        const float* __restrict__ bq, int* __restrict__ ctrs,
        int* __restrict__ listB, float* __restrict__ out_zq,
        float* __restrict__ out_idx) {
    __shared__ __align__(16) char smem[37888];
    short* seh = (short*)smem;                 // [0, 18432)
    short* sel = (short*)(smem + 18432);       // [18432, 36864)
    float* sbq = (float*)(smem + 36864);       // [36864, 37888)
    // phase-2 aliases (scan complete, barrier-separated):
    float* sz    = (float*)smem;               // 128*33*4 = 16896
    int*   scand = (int*)(smem + 16896);       // 128*4*4  = 2048
    int*   sdest = (int*)(smem + 18944);       // 512
    int*   sidx  = (int*)(smem + 19456);       // 512
    __shared__ int swt[2];
    __shared__ int sbase1;

    const int tid  = threadIdx.x;
    const int lane = tid & 63;
    const int wv   = tid >> 6;
    const int cloc = lane & 15, quad = lane >> 4;
    const int qbase = blockIdx.x * 128 + wv * 32;

    // A-fragments from z; keep the raw floats for the exact phase
    float  zf[2][8];
    bf16x8 azh[2], azl[2];
#pragma unroll
    for (int t = 0; t < 2; ++t) {
        const int q  = qbase + t * 16 + cloc;
        const int b  = q >> 12;
        const int hw = q & 4095;
        const float* zb = z + ((size_t)b * EMB_DIM + quad * 8) * HW + hw;
#pragma unroll
        for (int k = 0; k < 8; ++k) {
            float v = zb[(size_t)k * HW];
            zf[t][k] = v;
            unsigned short hb = bf16_rne(v);
            float hf = __uint_as_float((unsigned)hb << 16);
            azh[t][k] = (short)hb;
            azl[t][k] = (short)bf16_rne(v - hf);
        }
    }

    float m1[2][4], m2[2][4];
    int   i1[2][4];
#pragma unroll
    for (int t = 0; t < 2; ++t)
#pragma unroll
        for (int r = 0; r < 4; ++r) {
            m1[t][r] = 3.4e38f; m2[t][r] = 3.4e38f; i1[t][r] = 0;
        }

    for (int ch = 0; ch < 4; ++ch) {
        if (ch) __syncthreads();
#pragma unroll
        for (int i = 0; i < 8; ++i) {
            const int chunk = i * 256 + tid;           // 0..2047
            const int r = chunk >> 3, c = chunk & 7;   // 8 x 4-short pieces
            *(uint2*)&seh[r * ESTRIDE + c * 4] =
                *(const uint2*)(eh + (size_t)(ch * CHUNK + r) * 32 + c * 4);
            *(uint2*)&sel[r * ESTRIDE + c * 4] =
                *(const uint2*)(el + (size_t)(ch * CHUNK + r) * 32 + c * 4);
        }
        sbq[tid] = bq[ch * CHUNK + tid];
        __syncthreads();

        for (int jt = 0; jt < 16; ++jt) {
            const int row = jt * 16 + cloc;
            bf16x8 efh = lds_read8(&seh[row * ESTRIDE + quad * 8]);
            bf16x8 efl = lds_read8(&sel[row * ESTRIDE + quad * 8]);
            const float bqv = sbq[row];
            const int jts = ch * 16 + jt;
#pragma unroll
            for (int t = 0; t < 2; ++t) {
                f32x4 acc = {bqv, bqv, bqv, bqv};
                acc = __builtin_amdgcn_mfma_f32_16x16x32_bf16(azl[t], efh, acc, 0, 0, 0);
                acc = __builtin_amdgcn_mfma_f32_16x16x32_bf16(azh[t], efl, acc, 0, 0, 0);
                acc = __builtin_amdgcn_mfma_f32_16x16x32_bf16(azh[t], efh, acc, 0, 0, 0);
#pragma unroll
                for (int r = 0; r < 4; ++r) {
                    const float tt = acc[r];
                    const bool l1 = tt < m1[t][r];
                    m2[t][r] = __builtin_amdgcn_fmed3f(tt, m1[t][r], m2[t][r]);
                    m1[t][r] = fminf(m1[t][r], tt);
                    i1[t][r] = l1 ? jts : i1[t][r];
                }
            }
        }
    }
    __syncthreads();   // scan done everywhere; staging LDS may be reused

    // park z floats: sz[ql*33 + quad*8 + k]
#pragma unroll
    for (int t = 0; t < 2; ++t) {
        const int ql = wv * 32 + t * 16 + cloc;
#pragma unroll
        for (int k = 0; k < 8; ++k) sz[ql * 33 + quad * 8 + k] = zf[t][k];
    }

    // per-query global min across the 16 cloc lanes
    float g[2][4];
#pragma unroll
    for (int t = 0; t < 2; ++t)
#pragma unroll
        for (int r = 0; r < 4; ++r) g[t][r] = m1[t][r];
#pragma unroll
    for (int off = 1; off < 16; off <<= 1)
#pragma unroll
        for (int t = 0; t < 2; ++t)
#pragma unroll
            for (int r = 0; r < 4; ++r)
                g[t][r] = fminf(g[t][r], __shfl_xor(g[t][r], off, 64));

    // classification -> LDS, no atomics (ballot-prefix candidate slots)
#pragma unroll
    for (int t = 0; t < 2; ++t)
#pragma unroll
        for (int r = 0; r < 4; ++r) {
            const float thr = g[t][r] + MARGIN;
            const int   ql  = wv * 32 + t * 16 + quad * 4 + r;
            const bool  f1  = m1[t][r] <= thr;
            const bool  f2  = m2[t][r] <= thr;
            const unsigned long long b1 = __ballot(f1);
            const unsigned long long b2 = __ballot(f2);
            const unsigned mk1 = (unsigned)(b1 >> (quad * 16)) & 0xFFFFu;
            const unsigned mk2 = (unsigned)(b2 >> (quad * 16)) & 0xFFFFu;
            const int pc  = __popc(mk1);
            const int ldr = __ffs(mk1) - 1;   // mk1 != 0 (global-min lane)
            if (mk2 | (unsigned)(pc > 4)) {
                if (cloc == ldr) sdest[ql] = 5;
            } else {
                if (f1)
                    scand[(ql << 2) + __popc(mk1 & ((1u << cloc) - 1u))] =
                        i1[t][r] * 16 + cloc;
                if (cloc == ldr) sdest[ql] = pc;
            }
        }
    __syncthreads();

    // listB compaction (1 atomic/block) + exact rescore for pc 2..4
    int d = 0, pre = 0;
    if (tid < 128) {
        d = sdest[tid];
        const unsigned long long mB = __ballot(d == 5);
        pre = (int)__popcll(mB & ((1ull << lane) - 1ull));
        if (lane == 0) swt[tid >> 6] = (int)__popcll(mB);
    }
    __syncthreads();
    if (tid == 0) {
        const int tB = swt[0] + swt[1];
        sbase1 = tB ? atomicAdd(&ctrs[1], tB) : 0;
    }
    __syncthreads();
    if (tid < 128) {
        if (d == 5) {
            listB[sbase1 + ((tid >> 6) ? swt[0] : 0) + pre] =
                blockIdx.x * 128 + tid;
        } else if (d == 1) {
            sidx[tid] = scand[tid << 2];
        } else {
            const float* szp = &sz[tid * 33];
#define LOADZ2(c) const float z##c = szp[(c)];
            REPEAT32(LOADZ2)
#undef LOADZ2
            Z_SQ_A()
            unsigned long long bestk = ~0ull;
            for (int k = 0; k < d; ++k) {
                const int jv = scand[(tid << 2) + k];
                EXACT_KEY(jv)
            }
            sidx[tid] = (int)(unsigned)(bestk & 0xffffffffu);
        }
    }
    __syncthreads();

    // writeback: idx + z_q for all non-B queries (coalesced across tid)
    if (tid < 128 && d != 5) {
        const int n    = blockIdx.x * 128 + tid;
        const int bidx = sidx[tid];
        out_idx[n] = (float)bidx;
        const int b  = n >> 12;
        const int hw = n & 4095;
        const float4* er = (const float4*)(emb + (size_t)bidx * EMB_DIM);
        float* op = out_zq + (size_t)b * EMB_DIM * HW + hw;
#pragma unroll
        for (int c4 = 0; c4 < 8; ++c4) {
            float4 v = er[c4];
            op[(size_t)(c4 * 4 + 0) * HW] = v.x;
            op[(size_t)(c4 * 4 + 1) * HW] = v.y;
            op[(size_t)(c4 * 4 + 2) * HW] = v.z;
            op[(size_t)(c4 * 4 + 3) * HW] = v.w;
        }
    }
}

// ---- fixup: list B, block-per-query exact full scan + idx + z_q -----------
__global__ __launch_bounds__(256) void vq_fixup(
        const float* __restrict__ z, const float* __restrict__ emb,
        const float* __restrict__ bq, const int* __restrict__ ctrs,
        const int* __restrict__ listB, float* __restrict__ out_zq,
        float* __restrict__ out_idx) {
    __shared__ unsigned long long bs[256];
    const int tid = threadIdx.x;
    const int total = ctrs[1];

    for (int it = blockIdx.x; it < total; it += gridDim.x) {
        const int n  = listB[it];
        const int b  = n >> 12;
        const int hw = n & 4095;
        const float* zp = z + (size_t)b * EMB_DIM * HW + hw;  // broadcast
        REPEAT32(LOADZ)
        Z_SQ_A()
        unsigned long long bestk = ~0ull;
#pragma unroll
        for (int k = 0; k < 4; ++k) { const int jv = tid * 4 + k; EXACT_KEY(jv) }
        bs[tid] = bestk;
        __syncthreads();
        for (int off = 128; off > 0; off >>= 1) {
            if (tid < off && bs[tid + off] < bs[tid]) bs[tid] = bs[tid + off];
            __syncthreads();
        }
        const int bidx = (int)(unsigned)(bs[0] & 0xffffffffu);
        if (tid == 0) out_idx[n] = (float)bidx;
        if (tid < EMB_DIM)
            out_zq[(size_t)b * EMB_DIM * HW + (size_t)tid * HW + hw] =
                emb[(size_t)bidx * EMB_DIM + tid];
        __syncthreads();
    }
}

// ================== proven R7/R5 exhaustive fallback =======================
#define SCAN_GROUP4(j)                                                        \
    {                                                                         \
        const float* e = emb + (size_t)(j) * EMB_DIM;                         \
        const float bq0 = bq[(j) + 0], bq1 = bq[(j) + 1];                     \
        const float bq2 = bq[(j) + 2], bq3 = bq[(j) + 3];                     \
        float m0 = 0.0f, m1 = 0.0f, m2 = 0.0f, m3 = 0.0f;                     \
        REPEAT32(FMA_K)                                                       \
        float d0 = __fsub_rn(__fadd_rn(a, bq0), __fmul_rn(2.0f, m0));         \
        float d1 = __fsub_rn(__fadd_rn(a, bq1), __fmul_rn(2.0f, m1));         \
        float d2 = __fsub_rn(__fadd_rn(a, bq2), __fmul_rn(2.0f, m2));         \
        float d3 = __fsub_rn(__fadd_rn(a, bq3), __fmul_rn(2.0f, m3));         \
        if (d0 < best) { best = d0; bidx = (j) + 0; }                         \
        if (d1 < best) { best = d1; bidx = (j) + 1; }                         \
        if (d2 < best) { best = d2; bidx = (j) + 2; }                         \
        if (d3 < best) { best = d3; bidx = (j) + 3; }                         \
    }
#define FMA_K(k) \
        m0 = __fmaf_rn(z##k, e[0 * EMB_DIM + (k)], m0); \
        m1 = __fmaf_rn(z##k, e[1 * EMB_DIM + (k)], m1); \
        m2 = __fmaf_rn(z##k, e[2 * EMB_DIM + (k)], m2); \
        m3 = __fmaf_rn(z##k, e[3 * EMB_DIM + (k)], m3);

__global__ __launch_bounds__(256) void vq_sqnorm_kernel(
        const float* __restrict__ emb, float* __restrict__ bq) {
    int j = blockIdx.x * 256 + threadIdx.x;
    if (j < NUM_EMB) bq[j] = pairwise_sq32(emb + j * EMB_DIM);
}

__global__ __launch_bounds__(128, 4) void vq_partial_kernel(
        const float* __restrict__ z, const float* __restrict__ emb,
        const float* __restrict__ bq, unsigned long long* __restrict__ pk) {
    const int n  = blockIdx.x * 128 + threadIdx.x;
    const int b  = n >> 12;
    const int hw = n & 4095;
    const float* zp = z + (size_t)b * EMB_DIM * HW + hw;
    REPEAT32(LOADZ)
    Z_SQ_A()
    const int j0 = blockIdx.y * CODES_PER;
    float best = 3.4e38f;
    int   bidx = j0;
    for (int j = j0; j < j0 + CODES_PER; j += 4) SCAN_GROUP4(j)
    pk[(size_t)blockIdx.y * N_TOT + n] =
        ((unsigned long long)__float_as_uint(best) << 32) | (unsigned)bidx;
}

__global__ __launch_bounds__(256, 2) void vq_main_kernel(
        const float* __restrict__ z, const float* __restrict__ emb,
        const float* __restrict__ bq, float* __restrict__ out_zq,
        float* __restrict__ out_idx) {
    const int n  = blockIdx.x * 256 + threadIdx.x;
    const int b  = n >> 12;
    const int hw = n & 4095;
    const float* zp = z + (size_t)b * EMB_DIM * HW + hw;
    REPEAT32(LOADZ)
    Z_SQ_A()
    float best = 3.4e38f;
    int   bidx = 0;
    for (int j = 0; j < NUM_EMB; j += 4) SCAN_GROUP4(j)
    out_idx[n] = (float)bidx;
    const float* eb = emb + (size_t)bidx * EMB_DIM;
    float* op = out_zq + (size_t)b * EMB_DIM * HW + hw;
#pragma unroll
    for (int cc = 0; cc < EMB_DIM; ++cc) op[(size_t)cc * HW] = eb[cc];
}

__global__ __launch_bounds__(256) void vq_combine_kernel(
        const float* __restrict__ emb,
        const unsigned long long* __restrict__ pk,
        float* __restrict__ out_zq, float* __restrict__ out_idx) {
    const int n = blockIdx.x * 256 + threadIdx.x;
    unsigned long long m = pk[n];
#pragma unroll
    for (int y = 1; y < NSPLIT; ++y) {
        unsigned long long v = pk[(size_t)y * N_TOT + n];
        if (v < m) m = v;
    }
    const int bidx = (int)(unsigned)(m & 0xffffffffu);
    out_idx[n] = (float)bidx;
    const int b  = n >> 12;
    const int hw = n & 4095;
    const float* eb = emb + (size_t)bidx * EMB_DIM;
    float* op = out_zq + (size_t)b * EMB_DIM * HW + hw;
#pragma unroll
    for (int cc = 0; cc < EMB_DIM; ++cc) op[(size_t)cc * HW] = eb[cc];
}

extern "C" void kernel_launch(void* const* d_in, const int* in_sizes, int n_in,
                              void* d_out, int out_size, void* d_ws,
                              size_t ws_size, hipStream_t stream) {
    const float* z   = (const float*)d_in[0];
    const float* emb = (const float*)d_in[1];
    char* ws = (char*)d_ws;
    float* out0 = (float*)d_out;
    float* out1 = out0 + (size_t)BATCH * EMB_DIM * HW;

    if (ws_size >= WS_NEED) {
        float*          bq    = (float*)(ws + OFF_BQ);
        unsigned short* eh    = (unsigned short*)(ws + OFF_EH);
        unsigned short* el    = (unsigned short*)(ws + OFF_EL);
        int*            ctrs  = (int*)(ws + OFF_CTRS);
        int*            listB = (int*)(ws + OFF_LISTB);

        vq_prep_e<<<4, 256, 0, stream>>>(emb, bq, eh, el, ctrs);
        vq_filter<<<N_TOT / 128, 256, 0, stream>>>(z, emb, eh, el, bq, ctrs,
                                                   listB, out0, out1);
        vq_fixup<<<1024, 256, 0, stream>>>(z, emb, bq, ctrs, listB,
                                           out0, out1);
    } else if (ws_size >= WS_NEED_R7) {
        float* bq = (float*)ws;
        unsigned long long* pk = (unsigned long long*)(ws + 4096);
        vq_sqnorm_kernel<<<NUM_EMB / 256, 256, 0, stream>>>(emb, bq);
        vq_partial_kernel<<<dim3(N_TOT / 128, NSPLIT), 128, 0, stream>>>(
            z, emb, bq, pk);
        vq_combine_kernel<<<N_TOT / 256, 256, 0, stream>>>(emb, pk, out0, out1);
    } else {
        float* bq = (float*)ws;
        vq_sqnorm_kernel<<<NUM_EMB / 256, 256, 0, stream>>>(emb, bq);
        vq_main_kernel<<<N_TOT / 256, 256, 0, stream>>>(z, emb, bq, out0, out1);
    }
}